// Round 6
// baseline (120.456 us; speedup 1.0000x reference)
//
#include <hip/hip_runtime.h>
#include <hip/hip_cooperative_groups.h>

namespace cg = cooperative_groups;

#define HH 512
#define WW 512
#define NPIX (HH*WW)

// ---------------------------------------------------------------------------
// Single cooperative kernel: phase 1 computes the combined surface byte
// (bit0 = pred-surface, bit1 = gt-surface) for pixel (r, c) = (blockIdx.x,
// threadIdx.x); grid.sync(); phase 2 does the exact EDT (vertical batched
// global probes + horizontal batched LDS min-plus with exact early exit),
// masked reduction, and ticket-based finalize.
//
// Exactness: all distances are small integers (exact in fp32); sentinel
// (1e6 + steps) and its square round identically to the reference (same
// single fp32 ops on the same operands). Early exits only skip candidates
// whose contribution is provably >= current best.
// ---------------------------------------------------------------------------
__global__ __launch_bounds__(512, 4) void fused_kernel(
        const float* __restrict__ pred, const float* __restrict__ gt,
        unsigned char* __restrict__ mAB,
        double* __restrict__ partials, unsigned int* __restrict__ ticket,
        float* __restrict__ out) {
    cg::grid_group grid = cg::this_grid();
    __shared__ float2 s2[WW];
    __shared__ double lred[16];
    __shared__ int winner;

    int r = blockIdx.x;
    int c = threadIdx.x;
    int idx = r * WW + c;
    if (idx == 0) *ticket = 0u;          // ordered for phase 2 by grid.sync

    // ---- phase 1: surface byte (OOB loads skipped -> treated as 0) ----
    float pc_ = pred[idx];
    float pu = (r > 0)      ? pred[idx - WW] : 0.0f;
    float pd = (r < HH - 1) ? pred[idx + WW] : 0.0f;
    float pl = (c > 0)      ? pred[idx - 1]  : 0.0f;
    float pr = (c < WW - 1) ? pred[idx + 1]  : 0.0f;
    float gc = gt[idx];
    float gu = (r > 0)      ? gt[idx - WW] : 0.0f;
    float gd = (r < HH - 1) ? gt[idx + WW] : 0.0f;
    float gl = (c > 0)      ? gt[idx - 1]  : 0.0f;
    float gr = (c < WW - 1) ? gt[idx + 1]  : 0.0f;
    bool fa = (pc_ != 0.0f) &&
              !((pu != 0.0f) && (pd != 0.0f) && (pl != 0.0f) && (pr != 0.0f));
    bool fb = (gc != 0.0f) &&
              !((gu != 0.0f) && (gd != 0.0f) && (gl != 0.0f) && (gr != 0.0f));
    mAB[idx] = (unsigned char)((fa ? 1u : 0u) | (fb ? 2u : 0u));

    grid.sync();

    // ---- phase 2a: vertical nearest-feature distance, batched probes ----
    int foundA = fa ? 0 : -1;
    int foundB = fb ? 0 : -1;
    for (int kb = 1; kb < HH && (foundA < 0 || foundB < 0); kb += 4) {
        unsigned int mu[4], md[4];
        #pragma unroll
        for (int i = 0; i < 4; ++i) {
            int ku = kb + i;
            int ru = r - ku, rd = r + ku;
            mu[i] = (ru >= 0) ? (unsigned int)mAB[ru * WW + c] : 0u;
            md[i] = (rd < HH) ? (unsigned int)mAB[rd * WW + c] : 0u;
        }
        #pragma unroll
        for (int i = 0; i < 4; ++i) {
            unsigned int hit = mu[i] | md[i];
            if (foundA < 0 && (hit & 1u)) foundA = kb + i;
            if (foundB < 0 && (hit & 2u)) foundB = kb + i;
        }
    }
    float sent = 1e6f + (float)((r + 1 < HH - r) ? (r + 1) : (HH - r));
    float ga = (foundA >= 0) ? (float)foundA : sent;
    float gb = (foundB >= 0) ? (float)foundB : sent;
    s2[c] = make_float2(ga * ga, gb * gb);
    __syncthreads();

    // ---- phase 2b: horizontal min-plus, batched, exact early exit ----
    float2 o2 = s2[c];
    float besta = o2.x, bestb = o2.y;
    for (int kb = 1; kb < WW; kb += 4) {
        float kk2 = (float)(kb * kb);
        if (kk2 >= besta && kk2 >= bestb) break;
        #pragma unroll
        for (int i = 0; i < 4; ++i) {
            int k = kb + i;
            float k2 = (float)(k * k);
            int cl = c - k, cr = c + k;
            if (cl >= 0) {
                float2 g = s2[cl];
                besta = fminf(besta, g.x + k2);
                bestb = fminf(bestb, g.y + k2);
            }
            if (cr < WW) {
                float2 g = s2[cr];
                besta = fminf(besta, g.x + k2);
                bestb = fminf(bestb, g.y + k2);
            }
        }
    }

    // ---- phase 2c: masked reduction + ticket finalize ----
    float wA = fa ? 1.0f : 0.0f;
    float wB = fb ? 1.0f : 0.0f;
    // num = sum(dta * spm) + sum(dtb * sm); dta = dist to pred surface (bit0)
    double lnum = (double)(sqrtf(besta) * wB + sqrtf(bestb) * wA);
    double lden = (double)(wA + wB);
    for (int off = 32; off > 0; off >>= 1) {
        lnum += __shfl_down(lnum, off, 64);
        lden += __shfl_down(lden, off, 64);
    }
    int wv = c >> 6;
    if ((c & 63) == 0) { lred[wv] = lnum; lred[8 + wv] = lden; }
    __syncthreads();
    if (c == 0) {
        double n = 0.0, d = 0.0;
        #pragma unroll
        for (int i = 0; i < 8; ++i) { n += lred[i]; d += lred[8 + i]; }
        partials[2 * r]     = n;
        partials[2 * r + 1] = d;
        __threadfence();                         // release partials
        unsigned int old = atomicAdd(ticket, 1u);
        winner = (old == HH - 1) ? 1 : 0;
    }
    __syncthreads();

    if (winner) {                                // last block finalizes
        __threadfence();                         // acquire all partials
        double n = partials[2 * c];
        double d = partials[2 * c + 1];
        for (int off = 32; off > 0; off >>= 1) {
            n += __shfl_down(n, off, 64);
            d += __shfl_down(d, off, 64);
        }
        if ((c & 63) == 0) { lred[c >> 6] = n; lred[8 + (c >> 6)] = d; }
        __syncthreads();
        if (c == 0) {
            double nn = 0.0, dd = 0.0;
            #pragma unroll
            for (int i = 0; i < 8; ++i) { nn += lred[i]; dd += lred[8 + i]; }
            out[0] = (float)(nn / dd);
        }
    }
}

extern "C" void kernel_launch(void* const* d_in, const int* in_sizes, int n_in,
                              void* d_out, int out_size, void* d_ws, size_t ws_size,
                              hipStream_t stream) {
    const float* pred = (const float*)d_in[0];
    const float* gt   = (const float*)d_in[1];
    float* out = (float*)d_out;

    char* ws = (char*)d_ws;
    unsigned int* tick = (unsigned int*)ws;                      // 4 B
    double* partials   = (double*)(ws + 256);                    // 8 KB
    unsigned char* mAB = (unsigned char*)(ws + 256 + 8192);      // 256 KB

    void* args[] = { (void*)&pred, (void*)&gt, (void*)&mAB,
                     (void*)&partials, (void*)&tick, (void*)&out };
    hipLaunchCooperativeKernel((const void*)fused_kernel, dim3(HH), dim3(WW),
                               args, 0, stream);
}

// Round 7
// 82.570 us; speedup vs baseline: 1.4588x; 1.4588x over previous
//
#include <hip/hip_runtime.h>

#define HH 512
#define WW 512
#define MAGIC 0x13579BDFu

// ---------------------------------------------------------------------------
// Single NON-cooperative kernel. Block = row r (512 threads, c = tid).
// No precomputed surface mask: a surface test at any probe row is recomputed
// from the 5-point stencil of pred/gt (both L2-resident, OOB = background).
// surface(rr,c) = x[rr,c]!=0 && !(all 4 neighbors !=0), neighbors OOB -> 0.
//
// Vertical: rows r+-1..r+-6 evaluated from one 82-load batch (single vmcnt
// wait); rare per-k fallback for unresolved lanes. Exact: finds min |dr|.
// Horizontal: d2[c] = min_j(g2[j] + (c-j)^2) with exact early exit
// (k^2 >= best => no farther j can win since g2 >= 0).
// Finalize: per-row partials + MAGIC flags (poison-proof, no pre-zeroed
// ticket needed); block 0 spins on flags with device-scope atomics, reduces.
// fp32 roundings identical to the reference (same single ops, same operands;
// all distances are small integers, sentinel 1e6+k exact in fp32).
// ---------------------------------------------------------------------------
__global__ __launch_bounds__(512) void fused_kernel(
        const float* __restrict__ pred, const float* __restrict__ gt,
        double* __restrict__ partials, unsigned int* __restrict__ flags,
        float* __restrict__ out) {
    __shared__ float2 s2[WW];
    __shared__ double lred[16];
    int r = blockIdx.x;
    int c = threadIdx.x;

    // ---- batched stencil loads: centers rows r-7..r+7, l/r rows r-6..r+6 ----
    float pc[15], gc[15];
    #pragma unroll
    for (int j = 0; j < 15; ++j) {
        int rr = r - 7 + j;
        bool v = (rr >= 0) && (rr < HH);
        pc[j] = v ? pred[rr * WW + c] : 0.0f;
        gc[j] = v ? gt[rr * WW + c]   : 0.0f;
    }
    float pl[13], pr[13], gl[13], gr[13];
    #pragma unroll
    for (int m = 0; m < 13; ++m) {
        int rr = r - 6 + m;
        bool v = (rr >= 0) && (rr < HH);
        pl[m] = (v && c > 0)      ? pred[rr * WW + c - 1] : 0.0f;
        pr[m] = (v && c < WW - 1) ? pred[rr * WW + c + 1] : 0.0f;
        gl[m] = (v && c > 0)      ? gt[rr * WW + c - 1]   : 0.0f;
        gr[m] = (v && c < WW - 1) ? gt[rr * WW + c + 1]   : 0.0f;
    }

    // own surface bits (row r: center j=7, lr m=6)
    bool fa = (pc[7] != 0.0f) && !((pc[6] != 0.0f) && (pc[8] != 0.0f) &&
                                   (pl[6] != 0.0f) && (pr[6] != 0.0f));
    bool fb = (gc[7] != 0.0f) && !((gc[6] != 0.0f) && (gc[8] != 0.0f) &&
                                   (gl[6] != 0.0f) && (gr[6] != 0.0f));

    // ---- vertical nearest-surface distance, k = 1..6 from the batch ----
    int foundA = fa ? 0 : -1;
    int foundB = fb ? 0 : -1;
    #pragma unroll
    for (int k = 1; k <= 6; ++k) {
        // down row r+k: center j=7+k, neighbors j=6+k/8+k, lr m=6+k
        bool saD = (pc[7+k] != 0.0f) && !((pc[6+k] != 0.0f) && (pc[8+k] != 0.0f) &&
                                          (pl[6+k] != 0.0f) && (pr[6+k] != 0.0f));
        bool sbD = (gc[7+k] != 0.0f) && !((gc[6+k] != 0.0f) && (gc[8+k] != 0.0f) &&
                                          (gl[6+k] != 0.0f) && (gr[6+k] != 0.0f));
        // up row r-k: center j=7-k, neighbors j=6-k/8-k, lr m=6-k
        bool saU = (pc[7-k] != 0.0f) && !((pc[6-k] != 0.0f) && (pc[8-k] != 0.0f) &&
                                          (pl[6-k] != 0.0f) && (pr[6-k] != 0.0f));
        bool sbU = (gc[7-k] != 0.0f) && !((gc[6-k] != 0.0f) && (gc[8-k] != 0.0f) &&
                                          (gl[6-k] != 0.0f) && (gr[6-k] != 0.0f));
        if (foundA < 0 && (saD || saU)) foundA = k;
        if (foundB < 0 && (sbD || sbU)) foundB = k;
    }
    // rare fallback (P ~ 1e-3 per lane)
    for (int k = 7; k < HH && (foundA < 0 || foundB < 0); ++k) {
        int rd = r + k, ru = r - k;
        float a0=0,a1=0,a2=0,a3=0,a4=0, b0=0,b1=0,b2=0,b3=0,b4=0;
        float e0=0,e1=0,e2=0,e3=0,e4=0, h0=0,h1=0,h2=0,h3=0,h4=0;
        if (rd < HH) {
            a0 = pred[rd*WW+c];
            a1 = pred[(rd-1)*WW+c];
            a2 = (rd+1 < HH) ? pred[(rd+1)*WW+c] : 0.0f;
            a3 = (c > 0)      ? pred[rd*WW+c-1] : 0.0f;
            a4 = (c < WW-1)   ? pred[rd*WW+c+1] : 0.0f;
            b0 = gt[rd*WW+c];
            b1 = gt[(rd-1)*WW+c];
            b2 = (rd+1 < HH) ? gt[(rd+1)*WW+c] : 0.0f;
            b3 = (c > 0)      ? gt[rd*WW+c-1] : 0.0f;
            b4 = (c < WW-1)   ? gt[rd*WW+c+1] : 0.0f;
        }
        if (ru >= 0) {
            e0 = pred[ru*WW+c];
            e1 = (ru-1 >= 0) ? pred[(ru-1)*WW+c] : 0.0f;
            e2 = pred[(ru+1)*WW+c];
            e3 = (c > 0)      ? pred[ru*WW+c-1] : 0.0f;
            e4 = (c < WW-1)   ? pred[ru*WW+c+1] : 0.0f;
            h0 = gt[ru*WW+c];
            h1 = (ru-1 >= 0) ? gt[(ru-1)*WW+c] : 0.0f;
            h2 = gt[(ru+1)*WW+c];
            h3 = (c > 0)      ? gt[ru*WW+c-1] : 0.0f;
            h4 = (c < WW-1)   ? gt[ru*WW+c+1] : 0.0f;
        }
        bool saD = a0!=0.0f && !(a1!=0.0f && a2!=0.0f && a3!=0.0f && a4!=0.0f);
        bool sbD = b0!=0.0f && !(b1!=0.0f && b2!=0.0f && b3!=0.0f && b4!=0.0f);
        bool saU = e0!=0.0f && !(e1!=0.0f && e2!=0.0f && e3!=0.0f && e4!=0.0f);
        bool sbU = h0!=0.0f && !(h1!=0.0f && h2!=0.0f && h3!=0.0f && h4!=0.0f);
        if (foundA < 0 && (saD || saU)) foundA = k;
        if (foundB < 0 && (sbD || sbU)) foundB = k;
    }

    float sent = 1e6f + (float)((r + 1 < HH - r) ? (r + 1) : (HH - r));
    float ga = (foundA >= 0) ? (float)foundA : sent;
    float gb = (foundB >= 0) ? (float)foundB : sent;
    s2[c] = make_float2(ga * ga, gb * gb);
    __syncthreads();

    // ---- horizontal min-plus, batched, exact early exit ----
    float2 o2 = s2[c];
    float besta = o2.x, bestb = o2.y;
    for (int kb = 1; kb < WW; kb += 4) {
        float kk2 = (float)(kb * kb);
        if (kk2 >= besta && kk2 >= bestb) break;
        #pragma unroll
        for (int i = 0; i < 4; ++i) {
            int k = kb + i;
            float k2 = (float)(k * k);
            int cl = c - k, cr = c + k;
            if (cl >= 0) {
                float2 g = s2[cl];
                besta = fminf(besta, g.x + k2);
                bestb = fminf(bestb, g.y + k2);
            }
            if (cr < WW) {
                float2 g = s2[cr];
                besta = fminf(besta, g.x + k2);
                bestb = fminf(bestb, g.y + k2);
            }
        }
    }

    // ---- masked reduction ----
    float wA = fa ? 1.0f : 0.0f;
    float wB = fb ? 1.0f : 0.0f;
    // num = sum(dta * spm) + sum(dtb * sm); dta = dist to pred surface (A)
    double lnum = (double)(sqrtf(besta) * wB + sqrtf(bestb) * wA);
    double lden = (double)(wA + wB);
    for (int off = 32; off > 0; off >>= 1) {
        lnum += __shfl_down(lnum, off, 64);
        lden += __shfl_down(lden, off, 64);
    }
    int wv = c >> 6;
    if ((c & 63) == 0) { lred[wv] = lnum; lred[8 + wv] = lden; }
    __syncthreads();
    if (c == 0) {
        double n = 0.0, d = 0.0;
        #pragma unroll
        for (int i = 0; i < 8; ++i) { n += lred[i]; d += lred[8 + i]; }
        partials[2 * r]     = n;
        partials[2 * r + 1] = d;
        __threadfence();                          // release partials
        atomicExch(&flags[r], MAGIC);             // poison-proof "done" flag
    }

    // ---- block 0 finalizes: spin on flags, reduce 512 partials ----
    if (r == 0) {
        while (atomicOr(&flags[c], 0u) != MAGIC) {
            __builtin_amdgcn_s_sleep(2);
        }
        __threadfence();                          // acquire
        double n = atomicAdd(&partials[2 * c], 0.0);      // coherent reads
        double d = atomicAdd(&partials[2 * c + 1], 0.0);
        for (int off = 32; off > 0; off >>= 1) {
            n += __shfl_down(n, off, 64);
            d += __shfl_down(d, off, 64);
        }
        __syncthreads();                          // lred reuse safe
        if ((c & 63) == 0) { lred[c >> 6] = n; lred[8 + (c >> 6)] = d; }
        __syncthreads();
        if (c == 0) {
            double nn = 0.0, dd = 0.0;
            #pragma unroll
            for (int i = 0; i < 8; ++i) { nn += lred[i]; dd += lred[8 + i]; }
            out[0] = (float)(nn / dd);
        }
    }
}

extern "C" void kernel_launch(void* const* d_in, const int* in_sizes, int n_in,
                              void* d_out, int out_size, void* d_ws, size_t ws_size,
                              hipStream_t stream) {
    const float* pred = (const float*)d_in[0];
    const float* gt   = (const float*)d_in[1];
    float* out = (float*)d_out;

    char* ws = (char*)d_ws;
    double* partials    = (double*)(ws + 256);            // 512*2*8 = 8 KB
    unsigned int* flags = (unsigned int*)(ws + 256 + 8192); // 2 KB

    fused_kernel<<<HH, WW, 0, stream>>>(pred, gt, partials, flags, out);
}

// Round 8
// 75.525 us; speedup vs baseline: 1.5949x; 1.0933x over previous
//
#include <hip/hip_runtime.h>

#define HH 512
#define WW 512

// ---------------------------------------------------------------------------
// Single kernel, block = row r (512 threads, c = tid), NO grid sync, NO spin.
//
// Vertical surface search via column bitmasks:
//   each thread loads its own column's rows r-7..r+7 for both fields
//   (30 coalesced loads), packs "solid" (!=0) into a 15-bit mask, shares via
//   LDS; neighbor columns' masks give the 4-conn erosion bitwise:
//   surf = solid & ~(up & down & left & right)   (valid bits j=1..13,
//   rows r-6..r+6; OOB rows/cols are background via gating/zero).
//   Nearest surface row distance = clz/ffs on the up/down halves.
//   Rare fallback (no surface within +-6, P~1e-3/lane) probes per-k.
// Horizontal: d2[c] = min_j(g2[j] + (c-j)^2) in LDS, exact early exit
//   (k^2 >= best => no farther j can win since g2 >= 0).
// Finalize: per-row partials; last block (poison-based ticket: ws is 0xAA
//   before every launch, so base = 0xAAAAAAAA; also accept base 0) reduces.
// fp32 roundings identical to the reference (same single ops, same operands;
// distances are small integers, sentinel 1e6+k exact in fp32).
// ---------------------------------------------------------------------------
__global__ __launch_bounds__(512) void fused_kernel(
        const float* __restrict__ pred, const float* __restrict__ gt,
        double* __restrict__ partials, unsigned int* __restrict__ ticket,
        float* __restrict__ out) {
    __shared__ unsigned int smA[WW], smB[WW];
    __shared__ float2 s2[WW];
    __shared__ double lred[16];
    __shared__ int winner;
    int r = blockIdx.x;
    int c = threadIdx.x;

    // ---- own-column solid bitmasks, rows r-7..r+7 (bit j = row r-7+j) ----
    unsigned int sA = 0u, sB = 0u;
    #pragma unroll
    for (int j = 0; j < 15; ++j) {
        int rr = r - 7 + j;
        if (rr >= 0 && rr < HH) {
            if (pred[rr * WW + c] != 0.0f) sA |= (1u << j);
            if (gt[rr * WW + c]   != 0.0f) sB |= (1u << j);
        }
    }
    smA[c] = sA; smB[c] = sB;
    __syncthreads();
    unsigned int lA = (c > 0)      ? smA[c - 1] : 0u;
    unsigned int rA = (c < WW - 1) ? smA[c + 1] : 0u;
    unsigned int lB = (c > 0)      ? smB[c - 1] : 0u;
    unsigned int rB = (c < WW - 1) ? smB[c + 1] : 0u;

    // erosion survives iff center & all 4 neighbors solid (OOB = 0 handled)
    unsigned int surfA = (sA & ~((sA >> 1) & (sA << 1) & lA & rA)) & 0x3FFEu;
    unsigned int surfB = (sB & ~((sB >> 1) & (sB << 1) & lB & rB)) & 0x3FFEu;

    bool fa = (surfA >> 7) & 1u;
    bool fb = (surfB >> 7) & 1u;

    // ---- vertical nearest-surface distance from bitmasks (k = 1..6) ----
    unsigned int upA = surfA & 0x007Eu, dnA = surfA & 0x3F00u;
    unsigned int upB = surfB & 0x007Eu, dnB = surfB & 0x3F00u;
    int duA = upA ? (7 - (31 - __clz(upA))) : 99;
    int ddA = dnA ? (__ffs(dnA) - 8)        : 99;
    int duB = upB ? (7 - (31 - __clz(upB))) : 99;
    int ddB = dnB ? (__ffs(dnB) - 8)        : 99;
    int foundA = fa ? 0 : min(duA, ddA);
    int foundB = fb ? 0 : min(duB, ddB);
    if (foundA > 6) foundA = -1;
    if (foundB > 6) foundB = -1;

    // ---- rare fallback: probe k = 7.. with full 5-pt stencils ----
    for (int k = 7; k < HH && (foundA < 0 || foundB < 0); ++k) {
        int rd = r + k, ru = r - k;
        bool saD = false, sbD = false, saU = false, sbU = false;
        if (rd < HH) {
            float a0 = pred[rd*WW+c];
            float a1 = pred[(rd-1)*WW+c];
            float a2 = (rd+1 < HH) ? pred[(rd+1)*WW+c] : 0.0f;
            float a3 = (c > 0)      ? pred[rd*WW+c-1] : 0.0f;
            float a4 = (c < WW-1)   ? pred[rd*WW+c+1] : 0.0f;
            float b0 = gt[rd*WW+c];
            float b1 = gt[(rd-1)*WW+c];
            float b2 = (rd+1 < HH) ? gt[(rd+1)*WW+c] : 0.0f;
            float b3 = (c > 0)      ? gt[rd*WW+c-1] : 0.0f;
            float b4 = (c < WW-1)   ? gt[rd*WW+c+1] : 0.0f;
            saD = a0!=0.0f && !(a1!=0.0f && a2!=0.0f && a3!=0.0f && a4!=0.0f);
            sbD = b0!=0.0f && !(b1!=0.0f && b2!=0.0f && b3!=0.0f && b4!=0.0f);
        }
        if (ru >= 0) {
            float e0 = pred[ru*WW+c];
            float e1 = (ru-1 >= 0) ? pred[(ru-1)*WW+c] : 0.0f;
            float e2 = pred[(ru+1)*WW+c];
            float e3 = (c > 0)      ? pred[ru*WW+c-1] : 0.0f;
            float e4 = (c < WW-1)   ? pred[ru*WW+c+1] : 0.0f;
            float h0 = gt[ru*WW+c];
            float h1 = (ru-1 >= 0) ? gt[(ru-1)*WW+c] : 0.0f;
            float h2 = gt[(ru+1)*WW+c];
            float h3 = (c > 0)      ? gt[ru*WW+c-1] : 0.0f;
            float h4 = (c < WW-1)   ? gt[ru*WW+c+1] : 0.0f;
            saU = e0!=0.0f && !(e1!=0.0f && e2!=0.0f && e3!=0.0f && e4!=0.0f);
            sbU = h0!=0.0f && !(h1!=0.0f && h2!=0.0f && h3!=0.0f && h4!=0.0f);
        }
        if (foundA < 0 && (saD || saU)) foundA = k;
        if (foundB < 0 && (sbD || sbU)) foundB = k;
    }

    float sent = 1e6f + (float)((r + 1 < HH - r) ? (r + 1) : (HH - r));
    float ga = (foundA >= 0) ? (float)foundA : sent;
    float gb = (foundB >= 0) ? (float)foundB : sent;
    s2[c] = make_float2(ga * ga, gb * gb);
    __syncthreads();

    // ---- horizontal min-plus, batched, exact early exit ----
    float2 o2 = s2[c];
    float besta = o2.x, bestb = o2.y;
    for (int kb = 1; kb < WW; kb += 4) {
        float kk2 = (float)(kb * kb);
        if (kk2 >= besta && kk2 >= bestb) break;
        #pragma unroll
        for (int i = 0; i < 4; ++i) {
            int k = kb + i;
            float k2 = (float)(k * k);
            int cl = c - k, cr = c + k;
            if (cl >= 0) {
                float2 g = s2[cl];
                besta = fminf(besta, g.x + k2);
                bestb = fminf(bestb, g.y + k2);
            }
            if (cr < WW) {
                float2 g = s2[cr];
                besta = fminf(besta, g.x + k2);
                bestb = fminf(bestb, g.y + k2);
            }
        }
    }

    // ---- masked reduction ----
    float wA = fa ? 1.0f : 0.0f;
    float wB = fb ? 1.0f : 0.0f;
    // num = sum(dta * spm) + sum(dtb * sm); dta = dist to pred surface (A)
    double lnum = (double)(sqrtf(besta) * wB + sqrtf(bestb) * wA);
    double lden = (double)(wA + wB);
    for (int off = 32; off > 0; off >>= 1) {
        lnum += __shfl_down(lnum, off, 64);
        lden += __shfl_down(lden, off, 64);
    }
    int wv = c >> 6;
    if ((c & 63) == 0) { lred[wv] = lnum; lred[8 + wv] = lden; }
    __syncthreads();
    if (c == 0) {
        double n = 0.0, d = 0.0;
        #pragma unroll
        for (int i = 0; i < 8; ++i) { n += lred[i]; d += lred[8 + i]; }
        partials[2 * r]     = n;
        partials[2 * r + 1] = d;
        __threadfence();                          // release partials
        unsigned int old = atomicAdd(ticket, 1u);
        // ws is re-poisoned to 0xAA before every launch -> base 0xAAAAAAAA;
        // also accept base 0 (ranges cannot collide).
        winner = (old == 0xAAAAAAAAu + (unsigned)(HH - 1) ||
                  old == (unsigned)(HH - 1)) ? 1 : 0;
    }
    __syncthreads();

    if (winner) {                                 // last-finishing block
        __threadfence();                          // acquire all partials
        double n = atomicAdd(&partials[2 * c], 0.0);      // coherent reads
        double d = atomicAdd(&partials[2 * c + 1], 0.0);
        for (int off = 32; off > 0; off >>= 1) {
            n += __shfl_down(n, off, 64);
            d += __shfl_down(d, off, 64);
        }
        if ((c & 63) == 0) { lred[c >> 6] = n; lred[8 + (c >> 6)] = d; }
        __syncthreads();
        if (c == 0) {
            double nn = 0.0, dd = 0.0;
            #pragma unroll
            for (int i = 0; i < 8; ++i) { nn += lred[i]; dd += lred[8 + i]; }
            out[0] = (float)(nn / dd);
        }
    }
}

extern "C" void kernel_launch(void* const* d_in, const int* in_sizes, int n_in,
                              void* d_out, int out_size, void* d_ws, size_t ws_size,
                              hipStream_t stream) {
    const float* pred = (const float*)d_in[0];
    const float* gt   = (const float*)d_in[1];
    float* out = (float*)d_out;

    char* ws = (char*)d_ws;
    unsigned int* tick = (unsigned int*)ws;                 // 4 B (0xAA poison)
    double* partials   = (double*)(ws + 256);               // 8 KB

    fused_kernel<<<HH, WW, 0, stream>>>(pred, gt, partials, tick, out);
}

// Round 9
// 72.285 us; speedup vs baseline: 1.6664x; 1.0448x over previous
//
#include <hip/hip_runtime.h>

#define HH 512
#define WW 512
#define NPIX (HH*WW)

// ---------------------------------------------------------------------------
// Kernel 1: combined surface mask  bit0 = pred-surface, bit1 = gt-surface.
// S = p & ~erode(p), 4-connectivity, OOB = false. float4-in / uchar4-out.
// Thread 0 zero-inits the ticket (ws is re-poisoned before every launch).
// ---------------------------------------------------------------------------
__global__ __launch_bounds__(256) void surf_kernel(
        const float* __restrict__ pred, const float* __restrict__ gt,
        unsigned char* __restrict__ mAB, unsigned int* __restrict__ ticket) {
    int idx4 = blockIdx.x * 256 + threadIdx.x;       // 0..65535, 4 px each
    if (idx4 == 0) { *ticket = 0u; }
    if (idx4 >= NPIX / 4) return;
    int r  = idx4 >> 7;                              // 128 float4 per row
    int c4 = (idx4 & 127) << 2;

    unsigned char bits[4] = {0, 0, 0, 0};
    const float* srcs[2] = { pred, gt };
    #pragma unroll
    for (int f = 0; f < 2; ++f) {
        const float* x = srcs[f];
        float4 v = ((const float4*)x)[idx4];
        float4 u = (r > 0)      ? ((const float4*)x)[idx4 - 128] : make_float4(0,0,0,0);
        float4 d = (r < HH - 1) ? ((const float4*)x)[idx4 + 128] : make_float4(0,0,0,0);
        float lS = (c4 > 0)        ? x[r * WW + c4 - 1] : 0.0f;
        float rS = (c4 + 4 < WW)   ? x[r * WW + c4 + 4] : 0.0f;
        float vv[4] = { v.x, v.y, v.z, v.w };
        float uu[4] = { u.x, u.y, u.z, u.w };
        float dd[4] = { d.x, d.y, d.z, d.w };
        #pragma unroll
        for (int e = 0; e < 4; ++e) {
            int c = c4 + e;
            bool ctr = vv[e] != 0.0f;
            bool up  = (r > 0)      && (uu[e] != 0.0f);
            bool dn  = (r < HH - 1) && (dd[e] != 0.0f);
            bool lf  = (c > 0)      && ((e == 0 ? lS : vv[e - 1]) != 0.0f);
            bool rt  = (c < WW - 1) && ((e == 3 ? rS : vv[e + 1]) != 0.0f);
            if (ctr && !(up && dn && lf && rt)) bits[e] |= (1 << f);
        }
    }
    uchar4 out;
    out.x = bits[0]; out.y = bits[1]; out.z = bits[2]; out.w = bits[3];
    ((uchar4*)mAB)[idx4] = out;
}

// ---------------------------------------------------------------------------
// Kernel 2: fused EDT + masked reduction + finalize. Block = row r, c = tid.
// Vertical: nearest feature row probed in BATCHES of 4 (8 independent loads
// issued before any test -> one latency wait per batch, not four).
// Horizontal: d2[c] = min_j(g2[j] + (c-j)^2), batched the same way; exit when
// kb^2 >= best (skipped j's contribute >= best since g2 >= 0 — exact).
// fp32 roundings identical to the reference (same operands, same single ops).
// ---------------------------------------------------------------------------
__global__ __launch_bounds__(512) void edt_kernel(
        const unsigned char* __restrict__ mAB,
        double* __restrict__ partials, unsigned int* __restrict__ ticket,
        float* __restrict__ out) {
    __shared__ float2 s2[WW];
    __shared__ double lred[16];
    __shared__ int winner;
    int r = blockIdx.x;
    int c = threadIdx.x;

    unsigned int own = mAB[r * WW + c];
    bool fa = (own & 1u) != 0u;
    bool fb = (own & 2u) != 0u;

    // --- vertical nearest-feature distance, batched probes ---
    int foundA = fa ? 0 : -1;
    int foundB = fb ? 0 : -1;
    for (int kb = 1; kb < HH && (foundA < 0 || foundB < 0); kb += 4) {
        unsigned int mu[4], md[4];
        #pragma unroll
        for (int i = 0; i < 4; ++i) {
            int ku = kb + i;
            int ru = r - ku, rd = r + ku;
            mu[i] = (ru >= 0) ? (unsigned int)mAB[ru * WW + c] : 0u;
            md[i] = (rd < HH) ? (unsigned int)mAB[rd * WW + c] : 0u;
        }
        #pragma unroll
        for (int i = 0; i < 4; ++i) {
            unsigned int hit = mu[i] | md[i];
            if (foundA < 0 && (hit & 1u)) foundA = kb + i;
            if (foundB < 0 && (hit & 2u)) foundB = kb + i;
        }
    }
    float sent = 1e6f + (float)((r + 1 < HH - r) ? (r + 1) : (HH - r));
    float ga = (foundA >= 0) ? (float)foundA : sent;
    float gb = (foundB >= 0) ? (float)foundB : sent;
    s2[c] = make_float2(ga * ga, gb * gb);
    __syncthreads();

    // --- horizontal min-plus, batched with exact early exit ---
    float2 o2 = s2[c];
    float besta = o2.x, bestb = o2.y;
    for (int kb = 1; kb < WW; kb += 4) {
        float kk2 = (float)(kb * kb);
        if (kk2 >= besta && kk2 >= bestb) break;
        #pragma unroll
        for (int i = 0; i < 4; ++i) {
            int k = kb + i;
            float k2 = (float)(k * k);
            int cl = c - k, cr = c + k;
            if (cl >= 0) {
                float2 g = s2[cl];
                besta = fminf(besta, g.x + k2);
                bestb = fminf(bestb, g.y + k2);
            }
            if (cr < WW) {
                float2 g = s2[cr];
                besta = fminf(besta, g.x + k2);
                bestb = fminf(bestb, g.y + k2);
            }
        }
    }

    // --- masked reduction ---
    float wA = fa ? 1.0f : 0.0f;
    float wB = fb ? 1.0f : 0.0f;
    // num = sum(dta * spm) + sum(dtb * sm); dta = dist to pred surface (A = bit0)
    double lnum = (double)(sqrtf(besta) * wB + sqrtf(bestb) * wA);
    double lden = (double)(wA + wB);
    for (int off = 32; off > 0; off >>= 1) {
        lnum += __shfl_down(lnum, off, 64);
        lden += __shfl_down(lden, off, 64);
    }
    int wv = c >> 6;
    if ((c & 63) == 0) { lred[wv] = lnum; lred[8 + wv] = lden; }
    __syncthreads();
    if (c == 0) {
        double n = 0.0, d = 0.0;
        #pragma unroll
        for (int i = 0; i < 8; ++i) { n += lred[i]; d += lred[8 + i]; }
        partials[2 * r]     = n;
        partials[2 * r + 1] = d;
        __threadfence();                         // release partials
        unsigned int old = atomicAdd(ticket, 1u);
        winner = (old == HH - 1) ? 1 : 0;
    }
    __syncthreads();

    // --- last block finalizes: parallel sum of 512 row partials ---
    if (winner) {
        __threadfence();                         // acquire all partials
        double n = partials[2 * c];
        double d = partials[2 * c + 1];
        for (int off = 32; off > 0; off >>= 1) {
            n += __shfl_down(n, off, 64);
            d += __shfl_down(d, off, 64);
        }
        if ((c & 63) == 0) { lred[c >> 6] = n; lred[8 + (c >> 6)] = d; }
        __syncthreads();
        if (c == 0) {
            double nn = 0.0, dd = 0.0;
            #pragma unroll
            for (int i = 0; i < 8; ++i) { nn += lred[i]; dd += lred[8 + i]; }
            out[0] = (float)(nn / dd);
        }
    }
}

extern "C" void kernel_launch(void* const* d_in, const int* in_sizes, int n_in,
                              void* d_out, int out_size, void* d_ws, size_t ws_size,
                              hipStream_t stream) {
    const float* pred = (const float*)d_in[0];
    const float* gt   = (const float*)d_in[1];
    float* out = (float*)d_out;

    char* ws = (char*)d_ws;
    unsigned int* tick = (unsigned int*)ws;                      // 4 B
    double* partials   = (double*)(ws + 256);                    // 8 KB
    unsigned char* mAB = (unsigned char*)(ws + 256 + 8192);      // 256 KB

    surf_kernel<<<NPIX / 4 / 256, 256, 0, stream>>>(pred, gt, mAB, tick);
    edt_kernel<<<HH, 512, 0, stream>>>(mAB, partials, tick, out);
}